// Round 6
// baseline (170.486 us; speedup 1.0000x reference)
//
#include <hip/hip_runtime.h>
#include <stdint.h>

typedef unsigned short u16;
typedef unsigned int   u32;
typedef unsigned char  u8;
typedef signed char    s8;

#define B_    128
#define S_    1024
#define H_    1024
#define E_    256
#define EMB_  100
#define EMBP_ 128
#define V_    50000
#define NTOK_ (B_*S_)
#define FSINF 0x7F7F7F7F

typedef __attribute__((ext_vector_type(8))) short bf16x8;
typedef __attribute__((ext_vector_type(4))) float f32x4;
typedef __attribute__((ext_vector_type(4))) int   i32x4;

__device__ __forceinline__ u16 f2bf(float f){ u32 x=__float_as_uint(f); return (u16)((x + 0x7FFFu + ((x>>16)&1u))>>16); }
__device__ __forceinline__ float quantw(float w){ float r = rintf(w*16.f)*0.0625f; return fminf(fmaxf(r,-0.9375f),0.9375f); }

__device__ __forceinline__ void gll16(const void* g, void* l){
  __builtin_amdgcn_global_load_lds((const __attribute__((address_space(1))) void*)g,
                                   (__attribute__((address_space(3))) void*)l, 16, 0, 0);
}

// ---------------- merged prep ----------------

__global__ __launch_bounds__(256) void prep_all_k(const float* __restrict__ emb,
    const float* __restrict__ W1, const float* __restrict__ W2,
    const float* __restrict__ b2, const float* __restrict__ br2,
    u16* __restrict__ embhi, u16* __restrict__ w1hi, s8* __restrict__ qW2i,
    float* __restrict__ b2br2)
{
  int j = blockIdx.x*256 + threadIdx.x;
  const int N0 = V_*EMBP_;
  const int N1 = E_*EMBP_;
  const int N2 = H_*E_;
  const int N3 = H_;
  if (j < N0){
    int v = j >> 7, k = j & 127;
    embhi[j] = f2bf((k < EMB_) ? emb[v*EMB_ + k] : 0.f);
  } else if ((j -= N0) < N1){
    int n = j >> 7, k = j & 127;
    w1hi[j] = f2bf((k < EMB_) ? W1[n*EMB_ + k] : 0.f);
  } else if ((j -= N1) < N2){
    float q = rintf(W2[j]*16.f);
    qW2i[j] = (s8)(int)fminf(fmaxf(q, -15.f), 15.f);
  } else if ((j -= N2) < N3){
    b2br2[j] = b2[j] + br2[j];
  }
}

// ---------------- GEMM1: xq = quant(relu(gather(emb) @ W1^T + b1)) as int8 (x16) ----------------
// M=64 x N=128 tiles, K=128 staged once (single latency exposure). B fragments loaded
// directly from global (w1 is 64KB, L2-resident) BEFORE the barrier -> fully overlapped.

__global__ __launch_bounds__(256, 2) void gemm1_k(const int* __restrict__ inputs,
    const u16* __restrict__ embhi, const u16* __restrict__ w1hi,
    const float* __restrict__ b1, u8* __restrict__ xq)
{
  __shared__ __align__(16) char As[16384];   // 64 rows x 256 B, granule-XOR swizzled
  const int tid = threadIdx.x;
  const int bx = blockIdx.x;                 // 4096 blocks
  const int n0 = ((bx >> 3) & 1) * 128;      // paired n-blocks adjacent on same XCD
  const int m0 = ((bx & 7)*256 + (bx >> 4)) * 64;
  const int l = tid & 63, wid = tid >> 6;
  const int wm = wid & 1, wn = wid >> 1;     // wave tile 32t x 64n
  const int l4 = l >> 4;

  // B fragments direct from global (issue first; waited at first MFMA use)
  bf16x8 bfv[4][4];
  #pragma unroll
  for (int kk = 0; kk < 4; ++kk)
    #pragma unroll
    for (int ni = 0; ni < 4; ++ni){
      int row = n0 + wn*64 + ni*16 + (l & 15);
      bfv[kk][ni] = *(const bf16x8*)((const char*)w1hi + (size_t)row*256 + kk*64 + l4*16);
    }

  // stage A (64 gathered emb rows, full K) async -> LDS
  #pragma unroll
  for (int i = 0; i < 4; ++i){
    int p = tid + i*256, r = p >> 4, g = p & 15;
    long ga = (long)inputs[m0 + r];
    gll16((const char*)embhi + ga*256 + ((g ^ (r & 15))*16), As + p*16);
  }
  __syncthreads();

  f32x4 acc[2][4];
  #pragma unroll
  for (int mi = 0; mi < 2; ++mi)
    #pragma unroll
    for (int ni = 0; ni < 4; ++ni)
      acc[mi][ni] = (f32x4)0.f;

  #pragma unroll
  for (int kk = 0; kk < 4; ++kk){
    bf16x8 af[2];
    #pragma unroll
    for (int mi = 0; mi < 2; ++mi){
      int rA = wm*32 + mi*16 + (l & 15);
      af[mi] = *(const bf16x8*)&As[rA*256 + (((kk*4 + l4) ^ (rA & 15))*16)];
    }
    __builtin_amdgcn_s_setprio(1);
    #pragma unroll
    for (int mi = 0; mi < 2; ++mi)
      #pragma unroll
      for (int ni = 0; ni < 4; ++ni)
        acc[mi][ni] = __builtin_amdgcn_mfma_f32_16x16x32_bf16(af[mi], bfv[kk][ni], acc[mi][ni], 0, 0, 0);
    __builtin_amdgcn_s_setprio(0);
  }

  #pragma unroll
  for (int mi = 0; mi < 2; ++mi){
    #pragma unroll
    for (int ni = 0; ni < 4; ++ni){
      int col = n0 + wn*64 + ni*16 + (l & 15);
      float bv = b1[col];
      #pragma unroll
      for (int j = 0; j < 4; ++j){
        int row = m0 + wm*32 + mi*16 + l4*4 + j;
        float v = fmaxf(acc[mi][ni][j] + bv, 0.f);
        int q = (int)rintf(v*16.f);
        q = (q > 15) ? 15 : q;
        xq[(size_t)row*E_ + col] = (u8)q;
      }
    }
  }
}

// ---------------- GEMM2 + spike screen (no I materialization, no scan) ----------------
// Spike requires m > 0.5; with decay 0.2, m < max(I)/0.8, so: no I > 0.4 => no spike.
// Screen: running i32-max of MFMA accumulators (exact I), trip at 0.399 (1e-3 margin).
// B frags direct from global; A double-buffered 2x16KB; one barrier per subtile.

__global__ __launch_bounds__(256, 2) void gemm2_k(const s8* __restrict__ xq,
    const s8* __restrict__ qW2i, const float* __restrict__ b2br2, int* __restrict__ firstspike)
{
  __shared__ __align__(16) char LB[32768];   // A dbuf: 2 x (64t x 256k i8)
  const int tid = threadIdx.x;
  const int bx  = blockIdx.x;
  const int xcd = bx & 7, idx = bx >> 3;
  const int b   = xcd*16 + (idx >> 3);       // all 8 h-slices of a batch on one XCD
  const int n0  = (idx & 7) * 128;
  const int l = tid & 63, wid = tid >> 6;
  const int wm = wid >> 1, wn = wid & 1;     // wave tile 32t x 64h
  const int l4 = l >> 4;

  // B fragments + bias, direct from global (L2-resident)
  i32x4 bq[4][4];
  float be[4];
  #pragma unroll
  for (int ni = 0; ni < 4; ++ni){
    int row = n0 + wn*64 + ni*16 + (l & 15);
    #pragma unroll
    for (int ks = 0; ks < 4; ++ks)
      bq[ni][ks] = *(const i32x4*)(qW2i + (size_t)row*256 + ks*64 + l4*16);
    be[ni] = b2br2[row];
  }

  // stage A(0)
  const s8* Ab0 = xq + (size_t)b*S_*E_;
  #pragma unroll
  for (int i = 0; i < 4; ++i){
    int p = tid + i*256, r = p >> 4, g = p & 15;
    gll16(Ab0 + (size_t)r*256 + ((g ^ (r & 15))*16), LB + p*16);
  }
  __syncthreads();

  const int rA0 = wm*32 + (l & 15), rA1 = rA0 + 16;
  int rmax[4] = {(int)0x80000000, (int)0x80000000, (int)0x80000000, (int)0x80000000};

  for (int s = 0; s < 16; ++s){
    // prefetch next A tile into the other buffer (landed by end-of-iter barrier)
    if (s < 15){
      const s8* Ab = Ab0 + (size_t)(s + 1)*64*256;
      char* dst = LB + ((s + 1) & 1)*16384;
      #pragma unroll
      for (int i = 0; i < 4; ++i){
        int p = tid + i*256, r = p >> 4, g = p & 15;
        gll16(Ab + (size_t)r*256 + ((g ^ (r & 15))*16), dst + p*16);
      }
    }
    const char* cur = LB + (s & 1)*16384;
    i32x4 acc[2][4];
    #pragma unroll
    for (int mi = 0; mi < 2; ++mi)
      #pragma unroll
      for (int ni = 0; ni < 4; ++ni)
        acc[mi][ni] = (i32x4)0;

    __builtin_amdgcn_s_setprio(1);
    #pragma unroll
    for (int ks = 0; ks < 4; ++ks){
      i32x4 a0 = *(const i32x4*)&cur[rA0*256 + (((ks*4 + l4) ^ (rA0 & 15))*16)];
      i32x4 a1 = *(const i32x4*)&cur[rA1*256 + (((ks*4 + l4) ^ (rA1 & 15))*16)];
      #pragma unroll
      for (int ni = 0; ni < 4; ++ni){
        acc[0][ni] = __builtin_amdgcn_mfma_i32_16x16x64_i8(a0, bq[ni][ks], acc[0][ni], 0, 0, 0);
        acc[1][ni] = __builtin_amdgcn_mfma_i32_16x16x64_i8(a1, bq[ni][ks], acc[1][ni], 0, 0, 0);
      }
    }
    __builtin_amdgcn_s_setprio(0);

    // running exact-I max (integer domain)
    #pragma unroll
    for (int ni = 0; ni < 4; ++ni)
      #pragma unroll
      for (int mi = 0; mi < 2; ++mi)
        #pragma unroll
        for (int j = 0; j < 4; ++j)
          rmax[ni] = max(rmax[ni], acc[mi][ni][j]);

    __syncthreads();   // drains prefetch vmcnt; all reads of cur done
  }

  bool trip = false;
  #pragma unroll
  for (int ni = 0; ni < 4; ++ni)
    trip = trip || ((float)rmax[ni]*0.00390625f + be[ni] > 0.399f);
  if (trip) atomicMin(&firstspike[b], 0);
}

// ---------------- exact fallback (spiking batches only; quantizes Wr2 on the fly) ----------------

__global__ __launch_bounds__(256) void fallback_k(const s8* __restrict__ xq, const s8* __restrict__ qW2i,
    const float* __restrict__ b2br2, const float* __restrict__ Wr2,
    const int* __restrict__ firstspike, float* __restrict__ sumspike)
{
  const int b = blockIdx.x;
  if (firstspike[b] >= S_) return;
  const int tid = threadIdx.x;
  __shared__ int slist[H_];
  __shared__ int scount;
  __shared__ s8 xrow[E_];
  float mem[4] = {0,0,0,0}, sp[4] = {0,0,0,0}, ss[4] = {0,0,0,0};

  for (int t = 0; t < S_; ++t){
    if (tid == 0) scount = 0;
    __syncthreads();
    #pragma unroll
    for (int j = 0; j < 4; ++j)
      if (sp[j] > 0.5f){ int k = atomicAdd(&scount, 1); slist[k] = tid + j*256; }
    if (tid < 64) ((int*)xrow)[tid] = ((const int*)(xq + (size_t)(b*S_ + t)*E_))[tid];
    __syncthreads();
    int sc = scount;
    #pragma unroll
    for (int j = 0; j < 4; ++j){
      int h = tid + j*256;
      const s8* wr = qW2i + (size_t)h*E_;
      int ia = 0;
      #pragma unroll 4
      for (int k = 0; k < E_; k += 4){
        ia += (int)xrow[k]*(int)wr[k] + (int)xrow[k+1]*(int)wr[k+1]
            + (int)xrow[k+2]*(int)wr[k+2] + (int)xrow[k+3]*(int)wr[k+3];
      }
      float Iv = (float)ia*(1.f/256.f) + b2br2[h];
      float rec = 0.f;
      for (int u = 0; u < sc; ++u) rec += quantw(Wr2[(size_t)h*H_ + slist[u]]);
      mem[j] = mem[j]*0.2f*(1.f - sp[j]) + Iv + rec;
    }
    #pragma unroll
    for (int j = 0; j < 4; ++j){ float ns = (mem[j] > 0.5f) ? 1.f : 0.f; sp[j] = ns; ss[j] += ns; }
    __syncthreads();
  }
  #pragma unroll
  for (int j = 0; j < 4; ++j)
    sumspike[((size_t)b << 10) + tid + j*256] = ss[j];
}

// ---------------- final tiny GEMM ----------------

__global__ __launch_bounds__(256) void final_k(const float* __restrict__ ss, const float* __restrict__ W3,
    const float* __restrict__ b3, float* __restrict__ out)
{
  int b = blockIdx.x, tid = threadIdx.x;
  float p0 = 0.f, p1 = 0.f;
  for (int h = tid; h < H_; h += 256){
    float s = ss[((size_t)b << 10) + h];
    p0 += s*W3[h]; p1 += s*W3[H_ + h];
  }
  #pragma unroll
  for (int o = 32; o > 0; o >>= 1){ p0 += __shfl_down(p0, o, 64); p1 += __shfl_down(p1, o, 64); }
  __shared__ float r0[4], r1[4];
  if ((tid & 63) == 0){ r0[tid >> 6] = p0; r1[tid >> 6] = p1; }
  __syncthreads();
  if (tid == 0){
    out[b*2 + 0] = r0[0] + r0[1] + r0[2] + r0[3] + b3[0];
    out[b*2 + 1] = r1[0] + r1[1] + r1[2] + r1[3] + b3[1];
  }
}

// ---------------- host ----------------

extern "C" void kernel_launch(void* const* d_in, const int* in_sizes, int n_in,
                              void* d_out, int out_size, void* d_ws, size_t ws_size,
                              hipStream_t stream)
{
  (void)in_sizes; (void)n_in; (void)out_size; (void)ws_size;
  const int*   inputs = (const int*)  d_in[0];
  const float* emb    = (const float*)d_in[1];
  const float* W1     = (const float*)d_in[2];
  const float* b1     = (const float*)d_in[3];
  const float* W2     = (const float*)d_in[4];
  const float* b2     = (const float*)d_in[5];
  const float* Wr2    = (const float*)d_in[6];
  const float* br2    = (const float*)d_in[7];
  const float* W3     = (const float*)d_in[8];
  const float* b3     = (const float*)d_in[9];
  float* out = (float*)d_out;
  char* ws = (char*)d_ws;

  size_t off = 0;
  auto alloc = [&](size_t bytes)->char*{
    char* p = ws + off; off = (off + bytes + 255) & ~(size_t)255; return p;
  };
  u16*   embhi    = (u16*)  alloc((size_t)V_*EMBP_*2);   // 12.8 MB
  u16*   w1hi     = (u16*)  alloc((size_t)E_*EMBP_*2);
  s8*    qW2i     = (s8*)   alloc((size_t)H_*E_);
  float* b2br2    = (float*)alloc((size_t)H_*4);
  u8*    xq       = (u8*)   alloc((size_t)NTOK_*E_);     // 32 MB
  float* sumspike = (float*)alloc((size_t)B_*H_*4);
  int*   firstspk = (int*)  alloc((size_t)B_*4);

  hipMemsetAsync(sumspike, 0,    (size_t)B_*H_*4, stream);
  hipMemsetAsync(firstspk, 0x7F, (size_t)B_*4,    stream);

  {
    const int total = V_*EMBP_ + E_*EMBP_ + H_*E_ + H_;
    prep_all_k<<<(total + 255)/256, 256, 0, stream>>>(emb, W1, W2, b2, br2,
                                                      embhi, w1hi, qW2i, b2br2);
  }
  gemm1_k<<<4096, 256, 0, stream>>>(inputs, embhi, w1hi, b1, xq);
  gemm2_k<<<1024, 256, 0, stream>>>((const s8*)xq, qW2i, b2br2, firstspk);
  fallback_k<<<B_, 256, 0, stream>>>((const s8*)xq, qW2i, b2br2, Wr2, firstspk, sumspike);
  final_k<<<B_, 256, 0, stream>>>(sumspike, W3, b3, out);
}